// Round 1
// baseline (487.313 us; speedup 1.0000x reference)
//
#include <hip/hip_runtime.h>
#include <hip/hip_bf16.h>
#include <math.h>

// ---------- types ----------
typedef __bf16 bf16_t;
typedef __bf16 bf16x8 __attribute__((ext_vector_type(8)));
typedef __bf16 bf16x4 __attribute__((ext_vector_type(4)));
typedef float  f32x4  __attribute__((ext_vector_type(4)));

#define B_ 4
#define S_ 4096
#define D_ 1024
#define N_ 256
#define M_ (B_*S_)   // 16384

__device__ __forceinline__ float sigmoidf_(float x){ return 1.0f/(1.0f+expf(-x)); }

// ---------- weight transpose + cast: in f32 [R][C] -> out bf16 [C][R] ----------
__global__ void transpose_cast(const float* __restrict__ in, bf16_t* __restrict__ out,
                               int R, int C){
    __shared__ float tile[32][33];
    int c0 = blockIdx.x*32, r0 = blockIdx.y*32;
    int tx = threadIdx.x, ty = threadIdx.y;       // x:0..31, y:0..7
    #pragma unroll
    for (int i=0;i<32;i+=8){
        tile[ty+i][tx] = in[(size_t)(r0+ty+i)*C + (c0+tx)];
    }
    __syncthreads();
    #pragma unroll
    for (int i=0;i<32;i+=8){
        out[(size_t)(c0+ty+i)*R + (r0+tx)] = (bf16_t)tile[tx][ty+i];
    }
}

// ---------- LayerNorm: x f32 [M][D] -> h bf16 ----------
__global__ void ln_kernel(const float* __restrict__ x, const float* __restrict__ gw,
                          const float* __restrict__ bw, bf16_t* __restrict__ h){
    int row = blockIdx.x;
    int t = threadIdx.x;                           // 256 threads, 4 elems each
    float4 v = ((const float4*)(x + (size_t)row*D_))[t];
    float s = v.x+v.y+v.z+v.w;
    float q = v.x*v.x+v.y*v.y+v.z*v.z+v.w*v.w;
    #pragma unroll
    for (int o=1;o<64;o<<=1){ s += __shfl_xor(s,o,64); q += __shfl_xor(q,o,64); }
    __shared__ float sw[4], sq[4];
    int wid = t>>6;
    if ((t&63)==0){ sw[wid]=s; sq[wid]=q; }
    __syncthreads();
    s = sw[0]+sw[1]+sw[2]+sw[3];
    q = sq[0]+sq[1]+sq[2]+sq[3];
    float mu = s*(1.0f/D_);
    float rs = rsqrtf(q*(1.0f/D_) - mu*mu + 1e-5f);
    float4 gv = ((const float4*)gw)[t];
    float4 bv = ((const float4*)bw)[t];
    bf16x4 o4;
    o4[0] = (bf16_t)((v.x-mu)*rs*gv.x + bv.x);
    o4[1] = (bf16_t)((v.y-mu)*rs*gv.y + bv.y);
    o4[2] = (bf16_t)((v.z-mu)*rs*gv.z + bv.z);
    o4[3] = (bf16_t)((v.w-mu)*rs*gv.w + bv.w);
    *(bf16x4*)(h + (size_t)row*D_ + t*4) = o4;
}

// ---------- depthwise conv1d k=3 pad=1 along S (cross-correlation, XLA semantics) ----------
__global__ void conv_kernel(const bf16_t* __restrict__ h, const float* __restrict__ w,
                            const float* __restrict__ mb, bf16_t* __restrict__ mix){
    int idx = blockIdx.x*256 + threadIdx.x;        // 16384*128 total, 8 d-elems per thread
    int g8  = idx & 127;
    int row = idx >> 7;                            // b*S + s
    int s   = row & (S_-1);
    int d0  = g8*8;
    const bf16_t* hr = h + (size_t)row*D_ + d0;
    bf16x8 cur = *(const bf16x8*)hr;
    bf16x8 prv, nxt;
    #pragma unroll
    for (int i=0;i<8;i++){ prv[i]=(bf16_t)0.0f; nxt[i]=(bf16_t)0.0f; }
    if (s > 0)      prv = *(const bf16x8*)(hr - D_);
    if (s < S_-1)   nxt = *(const bf16x8*)(hr + D_);
    bf16x8 ov;
    #pragma unroll
    for (int i=0;i<8;i++){
        int d = d0+i;
        float o = (float)prv[i]*w[d*3] + (float)cur[i]*w[d*3+1] + (float)nxt[i]*w[d*3+2] + mb[d];
        ov[i] = (bf16_t)o;
    }
    *(bf16x8*)(mix + (size_t)row*D_ + d0) = ov;
}

// ---------- MFMA GEMM: C[M][Nn] = A[M][K] (bf16) @ Bt[Nn][K]^T (bf16), fp32 acc ----------
// 128x128 tile, BK=32, 4 waves (2x2), 4x4 16x16x32 tiles per wave.
// MODE 0: o0 = bf16 tanh(acc+b0)         (u)
// MODE 1: o0 = bf16 sigmoid(acc+b0)      (g)
// MODE 2: split cat N=768 -> xs/dc/sel f32 buffers (stride 256), tanh/sig/sig
// MODE 3: z = g*(acc+b0) + (1-g)*u -> bf16 o0
// MODE 4: o0 = f32 resid + acc + b0      (final residual out)
#define LDSW 48
template<int MODE>
__global__ __launch_bounds__(256)
void gemm_kernel(const bf16_t* __restrict__ A, const bf16_t* __restrict__ Bt,
                 int K, int Nn,
                 const float* __restrict__ b0, const float* __restrict__ b1,
                 const float* __restrict__ b2,
                 void* __restrict__ o0, void* __restrict__ o1, void* __restrict__ o2,
                 const bf16_t* __restrict__ gbuf, const bf16_t* __restrict__ ubuf,
                 const float* __restrict__ resid){
    __shared__ bf16_t As[128*LDSW];
    __shared__ bf16_t Bs[128*LDSW];
    int tid  = threadIdx.x;
    int m0   = blockIdx.x*128;
    int n0   = blockIdx.y*128;
    int wave = tid>>6, lane = tid&63;
    int wm = (wave>>1)*64, wn = (wave&1)*64;
    int lm = lane&15, quad = lane>>4;

    f32x4 acc[4][4];
    #pragma unroll
    for (int i=0;i<4;i++)
        #pragma unroll
        for (int j=0;j<4;j++)
            #pragma unroll
            for (int r=0;r<4;r++) acc[i][j][r]=0.0f;

    int ar = tid>>2;            // 0..63
    int ac = (tid&3)*8;         // 0,8,16,24

    for (int k0=0; k0<K; k0+=32){
        bf16x8 a0 = *(const bf16x8*)&A [(size_t)(m0+ar   )*K + k0+ac];
        bf16x8 a1 = *(const bf16x8*)&A [(size_t)(m0+ar+64)*K + k0+ac];
        bf16x8 g0 = *(const bf16x8*)&Bt[(size_t)(n0+ar   )*K + k0+ac];
        bf16x8 g1 = *(const bf16x8*)&Bt[(size_t)(n0+ar+64)*K + k0+ac];
        __syncthreads();
        *(bf16x8*)&As[(ar   )*LDSW + ac] = a0;
        *(bf16x8*)&As[(ar+64)*LDSW + ac] = a1;
        *(bf16x8*)&Bs[(ar   )*LDSW + ac] = g0;
        *(bf16x8*)&Bs[(ar+64)*LDSW + ac] = g1;
        __syncthreads();
        bf16x8 aF[4], bF[4];
        #pragma unroll
        for (int i=0;i<4;i++){
            aF[i] = *(const bf16x8*)&As[(wm+i*16+lm)*LDSW + quad*8];
            bF[i] = *(const bf16x8*)&Bs[(wn+i*16+lm)*LDSW + quad*8];
        }
        #pragma unroll
        for (int i=0;i<4;i++)
            #pragma unroll
            for (int j=0;j<4;j++)
                acc[i][j] = __builtin_amdgcn_mfma_f32_16x16x32_bf16(aF[i], bF[j], acc[i][j], 0,0,0);
    }

    // epilogue: C[row][col], row=(lane>>4)*4+reg, col=lane&15  [verified layout]
    #pragma unroll
    for (int i=0;i<4;i++){
        #pragma unroll
        for (int j=0;j<4;j++){
            #pragma unroll
            for (int r=0;r<4;r++){
                int row = m0 + wm + i*16 + quad*4 + r;
                int col = n0 + wn + j*16 + lm;
                float v = acc[i][j][r];
                if (MODE==0){
                    ((bf16_t*)o0)[(size_t)row*Nn + col] = (bf16_t)tanhf(v + b0[col]);
                } else if (MODE==1){
                    ((bf16_t*)o0)[(size_t)row*Nn + col] = (bf16_t)sigmoidf_(v + b0[col]);
                } else if (MODE==2){
                    int sub = col>>8, cc = col&255;
                    const float* bp = (sub==0)?b0:((sub==1)?b1:b2);
                    float val = v + bp[cc];
                    float rres = (sub==0)?tanhf(val):sigmoidf_(val);
                    float* op = (sub==0)?(float*)o0:((sub==1)?(float*)o1:(float*)o2);
                    op[(size_t)row*N_ + cc] = rres;
                } else if (MODE==3){
                    float yv = v + b0[col];
                    float gv = (float)gbuf[(size_t)row*D_ + col];
                    float uv = (float)ubuf[(size_t)row*D_ + col];
                    ((bf16_t*)o0)[(size_t)row*Nn + col] = (bf16_t)(gv*yv + (1.0f-gv)*uv);
                } else { // MODE 4
                    ((float*)o0)[(size_t)row*Nn + col] = resid[(size_t)row*Nn + col] + v + b0[col];
                }
            }
        }
    }
}

// ---------- chunked affine scan: state = d*state + (1-d)*x, 64 chunks of 64 ----------
__global__ void scan_p1(const float* __restrict__ dc, const float* __restrict__ xs,
                        float* __restrict__ aggA, float* __restrict__ aggB){
    int bc = blockIdx.x;            // b*64 + chunk
    int b = bc>>6, ch = bc&63;
    int n = threadIdx.x;
    size_t base = ((size_t)b*S_ + ch*64)*N_ + n;
    float A = 1.0f, Bc = 0.0f;
    for (int t=0;t<64;t++){
        float d = dc[base + (size_t)t*N_];
        float x = xs[base + (size_t)t*N_];
        A  = d*A;
        Bc = d*Bc + (1.0f-d)*x;
    }
    aggA[(size_t)bc*N_+n]=A; aggB[(size_t)bc*N_+n]=Bc;
}

__global__ void scan_p2(const float* __restrict__ aggA, const float* __restrict__ aggB,
                        float* __restrict__ pre){
    int b = blockIdx.x, n = threadIdx.x;
    float s = 0.0f;
    for (int ch=0; ch<64; ch++){
        size_t i = ((size_t)b*64+ch)*N_+n;
        pre[i] = s;
        s = aggA[i]*s + aggB[i];
    }
}

__global__ void scan_p3(const float* __restrict__ dc, const float* __restrict__ xs,
                        const float* __restrict__ sel, const float* __restrict__ pre,
                        bf16_t* __restrict__ ss){
    int bc = blockIdx.x;
    int b = bc>>6, ch = bc&63;
    int n = threadIdx.x;
    size_t base = ((size_t)b*S_ + ch*64)*N_ + n;
    float s = pre[(size_t)bc*N_+n];
    for (int t=0;t<64;t++){
        size_t i = base + (size_t)t*N_;
        float d = dc[i], x = xs[i];
        s = d*s + (1.0f-d)*x;
        ss[i] = (bf16_t)(sel[i]*s);
    }
}

// ---------- launch ----------
extern "C" void kernel_launch(void* const* d_in, const int* in_sizes, int n_in,
                              void* d_out, int out_size, void* d_ws, size_t ws_size,
                              hipStream_t stream){
    const float* x    = (const float*)d_in[0];
    const float* ln_g = (const float*)d_in[1];
    const float* ln_b = (const float*)d_in[2];
    const float* mixw = (const float*)d_in[3];
    const float* mixb = (const float*)d_in[4];
    const float* Wi   = (const float*)d_in[5];
    const float* bi   = (const float*)d_in[6];
    const float* Wsin = (const float*)d_in[7];
    const float* bsin = (const float*)d_in[8];
    const float* Wd   = (const float*)d_in[9];
    const float* bd   = (const float*)d_in[10];
    const float* Wsel = (const float*)d_in[11];
    const float* bsel = (const float*)d_in[12];
    const float* Wso  = (const float*)d_in[13];
    const float* bso  = (const float*)d_in[14];
    const float* Wg   = (const float*)d_in[15];
    const float* bg   = (const float*)d_in[16];
    const float* Wout = (const float*)d_in[17];
    const float* bout = (const float*)d_in[18];
    float* out = (float*)d_out;

    char* p = (char*)d_ws;
    auto alloc = [&](size_t bytes)->char*{ char* r=p; p += (bytes+255)&~(size_t)255; return r; };
    bf16_t* hB    = (bf16_t*)alloc((size_t)M_*D_*2);
    bf16_t* mixB  = (bf16_t*)alloc((size_t)M_*D_*2);
    bf16_t* uB    = (bf16_t*)alloc((size_t)M_*D_*2);
    bf16_t* gB    = (bf16_t*)alloc((size_t)M_*D_*2);
    bf16_t* ssB   = (bf16_t*)alloc((size_t)M_*N_*2);
    float*  xs    = (float*)alloc((size_t)M_*N_*4);
    float*  dc    = (float*)alloc((size_t)M_*N_*4);
    float*  sel   = (float*)alloc((size_t)M_*N_*4);
    bf16_t* WiT   = (bf16_t*)alloc(1024*1024*2);
    bf16_t* WcatT = (bf16_t*)alloc(768*1024*2);
    bf16_t* WgT   = (bf16_t*)alloc(1024*1024*2);
    bf16_t* WsoT  = (bf16_t*)alloc(1024*256*2);
    bf16_t* WoutT = (bf16_t*)alloc(1024*1024*2);
    float*  aggA  = (float*)alloc((size_t)4*64*256*4);
    float*  aggB  = (float*)alloc((size_t)4*64*256*4);
    float*  pre   = (float*)alloc((size_t)4*64*256*4);
    bf16_t* zB = mixB;   // alias: mixB is dead after the g-GEMM; z written after scan

    dim3 tb(32,8);
    // weight transposes (f32 [K][N] -> bf16 [N][K])
    transpose_cast<<<dim3(32,32), tb, 0, stream>>>(Wi,   WiT,            1024, 1024);
    transpose_cast<<<dim3(8, 32), tb, 0, stream>>>(Wsin, WcatT,          1024, 256);
    transpose_cast<<<dim3(8, 32), tb, 0, stream>>>(Wd,   WcatT+256*1024, 1024, 256);
    transpose_cast<<<dim3(8, 32), tb, 0, stream>>>(Wsel, WcatT+512*1024, 1024, 256);
    transpose_cast<<<dim3(32,32), tb, 0, stream>>>(Wg,   WgT,            1024, 1024);
    transpose_cast<<<dim3(32, 8), tb, 0, stream>>>(Wso,  WsoT,           256,  1024);
    transpose_cast<<<dim3(32,32), tb, 0, stream>>>(Wout, WoutT,          1024, 1024);

    ln_kernel  <<<M_, 256, 0, stream>>>(x, ln_g, ln_b, hB);
    conv_kernel<<<M_*128/256, 256, 0, stream>>>(hB, mixw, mixb, mixB);

    // u = tanh(mixed@Wi+bi)
    gemm_kernel<0><<<dim3(M_/128, 8), 256, 0, stream>>>(mixB, WiT, 1024, 1024,
        bi,nullptr,nullptr, uB,nullptr,nullptr, nullptr,nullptr,nullptr);
    // xs/dc/sel = act(mixed@[Wsin|Wd|Wsel]+b)
    gemm_kernel<2><<<dim3(M_/128, 6), 256, 0, stream>>>(mixB, WcatT, 1024, 768,
        bsin,bd,bsel, xs,dc,sel, nullptr,nullptr,nullptr);
    // g = sigmoid(mixed@Wg+bg)
    gemm_kernel<1><<<dim3(M_/128, 8), 256, 0, stream>>>(mixB, WgT, 1024, 1024,
        bg,nullptr,nullptr, gB,nullptr,nullptr, nullptr,nullptr,nullptr);

    scan_p1<<<4*64, 256, 0, stream>>>(dc, xs, aggA, aggB);
    scan_p2<<<4,    256, 0, stream>>>(aggA, aggB, pre);
    scan_p3<<<4*64, 256, 0, stream>>>(dc, xs, sel, pre, ssB);

    // z = g*(ss@Wso+bso) + (1-g)*u
    gemm_kernel<3><<<dim3(M_/128, 8), 256, 0, stream>>>(ssB, WsoT, 256, 1024,
        bso,nullptr,nullptr, zB,nullptr,nullptr, gB,uB,nullptr);
    // out = x + z@Wout + bout
    gemm_kernel<4><<<dim3(M_/128, 8), 256, 0, stream>>>(zB, WoutT, 1024, 1024,
        bout,nullptr,nullptr, out,nullptr,nullptr, nullptr,nullptr, x);
}